// Round 8
// baseline (3120.881 us; speedup 1.0000x reference)
//
#include <hip/hip_runtime.h>
#include <hip/hip_bf16.h>
#include <stdint.h>

typedef float f32x4 __attribute__((ext_vector_type(4)));
typedef short s16x8 __attribute__((ext_vector_type(8)));
typedef int i32x8 __attribute__((ext_vector_type(8)));

#define INV_SCALE (1.0f / 1024.0f)  // W pre-scaled x64, h x16
#define SCALE_ONE 0x7F7F7F7F        // E8M0 1.0 in every byte
#define LOG2E 1.4426950408889634f

__device__ __forceinline__ float sigm(float x) {
  return __builtin_amdgcn_rcpf(1.f + __builtin_amdgcn_exp2f(-LOG2E * x));
}
__device__ __forceinline__ ushort f2bf(float f) {
  union { float f; uint32_t u; } v; v.f = f;
  return (ushort)((v.u + 0x7FFFu + ((v.u >> 16) & 1)) >> 16);
}
__device__ __forceinline__ float bf2f(ushort b) {
  union { uint32_t u; float f; } v; v.u = ((uint32_t)b) << 16; return v.f;
}

// ---------------- prep: converts + permutes + flag reset ----------------
__global__ __launch_bounds__(256) void prep_kernel(
    const float* __restrict__ emb, const int* __restrict__ x,
    const float* __restrict__ Wih0, const float* __restrict__ Wih1,
    const float* __restrict__ bih0, const float* __restrict__ bhh0,
    const float* __restrict__ bih1, const float* __restrict__ bhh1,
    ushort* __restrict__ emb_bf, int* __restrict__ idx_ws,
    ushort* __restrict__ W0p, unsigned char* __restrict__ W1p8,
    float* __restrict__ b0p, float* __restrict__ b1p,
    unsigned int* __restrict__ done0)
{
  const int stride = gridDim.x * blockDim.x;
  const int gid = blockIdx.x * blockDim.x + threadIdx.x;
  for (int i = gid; i < 32000 * 128; i += stride) emb_bf[i] = f2bf(emb[i]);
  // idx_ws[t*128+b] = x[b*512+t]
  for (int i = gid; i < 65536; i += stride) idx_ws[i] = x[(i & 127) * 512 + (i >> 7)];
  // W0p[j][k] = Wih0[(j&3)*256 + (j>>2)][k]   (j = hid*4 + gate) bf16
  for (int i = gid; i < 1024 * 128; i += stride) {
    int j = i >> 7, k = i & 127;
    int p = ((j & 3) << 8) | (j >> 2);
    W0p[i] = f2bf(Wih0[p * 128 + k]);
  }
  // W1p8: RAW layout (row = gate*256+hid), fp8 e4m3 x64
  for (int i = gid; i < 131072; i += stride) {
    int q = __builtin_amdgcn_cvt_pk_fp8_f32(Wih1[2 * i] * 64.f, Wih1[2 * i + 1] * 64.f, 0, false);
    ((ushort*)W1p8)[i] = (ushort)(q & 0xFFFF);
  }
  for (int i = gid; i < 1024; i += stride) {
    int p = ((i & 3) << 8) | (i >> 2);
    b0p[i] = bih0[p] + bhh0[p];
    b1p[i] = bih1[p] + bhh1[p];
  }
  for (int i = gid; i < 128; i += stride) done0[i] = 0;  // reset chunk flags each launch
}

// ---------------- wide GEMM for xp0: xp[m][j] = emb[idx[m],:] @ W0p[j,:]^T + b0p[j] ----------------
template <int KD, bool GATHER>
__global__ __launch_bounds__(256) void gemm_xp(
    const ushort* __restrict__ A, const int* __restrict__ idx,
    const ushort* __restrict__ B, const float* __restrict__ bias,
    ushort* __restrict__ out)
{
  __shared__ ushort Al[128 * 72];
  __shared__ ushort Bl[128 * 72];
  const int tid = threadIdx.x;
  const int l = tid & 63, w = tid >> 6;
  const int wm = w >> 1, wn = w & 1;
  const int lr = l & 15, lg = l >> 4;
  const int m0 = blockIdx.x * 128, n0 = blockIdx.y * 128;

  f32x4 acc[4][4];
#pragma unroll
  for (int a = 0; a < 4; ++a)
#pragma unroll
    for (int b = 0; b < 4; ++b) acc[a][b] = (f32x4)0.f;

  const int srow = tid >> 1, sseg = tid & 1;
  for (int kk = 0; kk < KD / 64; ++kk) {
    const int k0 = kk * 64;
    size_t arow = GATHER ? (size_t)idx[m0 + srow] : (size_t)(m0 + srow);
    const uint4* sa = (const uint4*)(A + arow * KD + k0 + sseg * 32);
    uint4* da = (uint4*)(Al + srow * 72 + sseg * 32);
    da[0] = sa[0]; da[1] = sa[1]; da[2] = sa[2]; da[3] = sa[3];
    const uint4* sb = (const uint4*)(B + (size_t)(n0 + srow) * KD + k0 + sseg * 32);
    uint4* db = (uint4*)(Bl + srow * 72 + sseg * 32);
    db[0] = sb[0]; db[1] = sb[1]; db[2] = sb[2]; db[3] = sb[3];
    __syncthreads();
#pragma unroll
    for (int ks = 0; ks < 2; ++ks) {
      s16x8 av[4], bv[4];
#pragma unroll
      for (int mt = 0; mt < 4; ++mt)
        av[mt] = *(const s16x8*)(Al + (wm * 64 + mt * 16 + lr) * 72 + ks * 32 + lg * 8);
#pragma unroll
      for (int nt = 0; nt < 4; ++nt)
        bv[nt] = *(const s16x8*)(Bl + (wn * 64 + nt * 16 + lr) * 72 + ks * 32 + lg * 8);
#pragma unroll
      for (int mt = 0; mt < 4; ++mt)
#pragma unroll
        for (int nt = 0; nt < 4; ++nt)
          acc[mt][nt] = __builtin_amdgcn_mfma_f32_16x16x32_bf16(av[mt], bv[nt], acc[mt][nt], 0, 0, 0);
    }
    __syncthreads();
  }

#pragma unroll
  for (int nt = 0; nt < 4; ++nt) {
    const int colg = n0 + wn * 64 + nt * 16 + lr;
    const float bv = bias[colg];
#pragma unroll
    for (int mt = 0; mt < 4; ++mt) {
#pragma unroll
      for (int i = 0; i < 4; ++i) {
        const int rowg = m0 + wm * 64 + mt * 16 + 4 * lg + i;
        out[(size_t)rowg * 1024 + colg] = f2bf(acc[mt][nt][i] + bv);
      }
    }
  }
}

// ---------------- mega: layer-0 scan (WG 0-127) || layer-1 scan (WG 128-255) ----------------
// Chunked producer-consumer, 16 steps/chunk, pairwise per-batch flags.
// VGPR>64 forces 1 WG/CU (16 waves = 4/SIMD max at VGPR 65-128) -> 256 WGs all resident.
__global__ __launch_bounds__(1024) void mega_scan(
    const ushort* __restrict__ xp0, const float* __restrict__ Whh0,
    const float* __restrict__ Whh1, const unsigned char* __restrict__ W1p8,
    const float* __restrict__ b1p, unsigned char* __restrict__ hs8,
    unsigned int* __restrict__ done0, const float* __restrict__ fcw,
    const float* __restrict__ fcb, float* __restrict__ out)
{
  __shared__ __align__(16) unsigned char smem[38800];
  ushort* xpcu = (ushort*)smem;                 // [16][1024] bf16 xp chunk (layer 1)
  unsigned char* h0l = smem + 32768;            // [16][272]  fp8 h0 chunk stage
  unsigned char* hbb = smem + 37120;            // [2][320]   h ping-pong fp8
  float* hf = (float*)(smem + 37760);           // [260]      final h f32

  const int tid = threadIdx.x;
  const int l = tid & 63, w = tid >> 6;
  const int lr = l & 15, lg = l >> 4;
  const bool is0 = blockIdx.x < 128;
  const int b = is0 ? blockIdx.x : (blockIdx.x - 128);
  const float* Whh = is0 ? Whh0 : Whh1;
  const int hcol = 16 * w + lr;

  // W_hh fragments (fp8 x64): gate s, k-chunk kc; B col = 256*s + hcol, k = kc*128 + lg*32 + j
  i32x8 wf[4][2];
#pragma unroll
  for (int s = 0; s < 4; ++s) {
    const int n = 256 * s + hcol;
#pragma unroll
    for (int kc = 0; kc < 2; ++kc) {
      i32x8 r;
#pragma unroll
      for (int d = 0; d < 8; ++d) {
        const f32x4 v = *(const f32x4*)(Whh + (size_t)n * 256 + kc * 128 + lg * 32 + d * 4);
        int q = __builtin_amdgcn_cvt_pk_fp8_f32(v[0] * 64.f, v[1] * 64.f, 0, false);
        q = __builtin_amdgcn_cvt_pk_fp8_f32(v[2] * 64.f, v[3] * 64.f, q, true);
        r[d] = q;
      }
      wf[s][kc] = r;
    }
  }

  if (tid < 320) hbb[tid] = 0;  // h(-1) = 0 (buffer 0)
  float cc = 0.f;

  if (is0) {
    // ================= layer 0 (R7-verified step; + fp8 hs8 store + chunk flags) =================
    const ushort* xq0 = xp0 + (size_t)b * 1024 + (hcol << 2);
    uint2 xpv = *(const uint2*)xq0;
    __syncthreads();
    for (int t = 0; t < 512; ++t) {
      const unsigned char* hr = hbb + ((t & 1) * 320);
      unsigned char* hw = hbb + (((t & 1) ^ 1) * 320);
      i32x8 af[2];
#pragma unroll
      for (int kc = 0; kc < 2; ++kc) {
        const uint4* p = (const uint4*)(hr + kc * 128 + lg * 32);
        uint4 lo = p[0], hi = p[1];
        i32x8 a;
        a[0] = lo.x; a[1] = lo.y; a[2] = lo.z; a[3] = lo.w;
        a[4] = hi.x; a[5] = hi.y; a[6] = hi.z; a[7] = hi.w;
        af[kc] = a;
      }
      f32x4 acc0 = (f32x4)0.f, acc1 = (f32x4)0.f, acc2 = (f32x4)0.f, acc3 = (f32x4)0.f;
#pragma unroll
      for (int kc = 0; kc < 2; ++kc) {
        acc0 = __builtin_amdgcn_mfma_scale_f32_16x16x128_f8f6f4(af[kc], wf[0][kc], acc0, 0, 0, 0, SCALE_ONE, 0, SCALE_ONE);
        acc1 = __builtin_amdgcn_mfma_scale_f32_16x16x128_f8f6f4(af[kc], wf[1][kc], acc1, 0, 0, 0, SCALE_ONE, 0, SCALE_ONE);
        acc2 = __builtin_amdgcn_mfma_scale_f32_16x16x128_f8f6f4(af[kc], wf[2][kc], acc2, 0, 0, 0, SCALE_ONE, 0, SCALE_ONE);
        acc3 = __builtin_amdgcn_mfma_scale_f32_16x16x128_f8f6f4(af[kc], wf[3][kc], acc3, 0, 0, 0, SCALE_ONE, 0, SCALE_ONE);
      }
      uint2 xpn;
      if (t < 511) xpn = *(const uint2*)(xq0 + (size_t)(t + 1) * 131072);
      // gate phase: lg-specialized nonlinearity, shuffle-combined into lg0
      const uint word = (lg & 2) ? xpv.y : xpv.x;
      const uint h16 = (lg & 1) ? (word >> 16) : (word & 0xFFFFu);
      union { uint32_t u; float f; } xf; xf.u = h16 << 16;
      const float accsel = (lg & 2) ? ((lg & 1) ? acc3[0] : acc2[0])
                                    : ((lg & 1) ? acc1[0] : acc0[0]);
      const float p = accsel * INV_SCALE + xf.f;
      const float kk2 = (lg == 2) ? (2.f * LOG2E) : LOG2E;
      const float mm = (lg == 2) ? 2.f : 1.f;
      const float ex = __builtin_amdgcn_exp2f(kk2 * p);
      const float v = 1.f - mm * __builtin_amdgcn_rcpf(ex + 1.f);
      const float sf = __shfl(v, lr + 16);
      const float tg = __shfl(v, lr + 32);
      const float so = __shfl(v, lr + 48);
      cc = sf * cc + v * tg;
      const float e2 = __builtin_amdgcn_exp2f(2.f * LOG2E * cc);
      const float th = 1.f - 2.f * __builtin_amdgcn_rcpf(e2 + 1.f);
      const float h = so * th;
      if (lg == 0) {
        int q = __builtin_amdgcn_cvt_pk_fp8_f32(h * 16.f, h * 16.f, 0, false);
        hw[hcol] = (unsigned char)(q & 0xFF);
        hs8[(size_t)b * 131072 + (t << 8) + hcol] = (unsigned char)(q & 0xFF);
      }
      xpv = xpn;
      if ((t & 15) == 15) {
        __threadfence();   // each wave's hs8 writes device-visible
        __syncthreads();
        if (tid == 0)
          __hip_atomic_store(done0 + b, (unsigned)((t >> 4) + 1),
                             __ATOMIC_RELEASE, __HIP_MEMORY_SCOPE_AGENT);
      } else {
        __syncthreads();
      }
    }
  } else {
    // ================= layer 1: chunk GEMM (M=16 timesteps) + recurrence =================
    const f32x4 bias = *(const f32x4*)(b1p + (hcol << 2));
    __syncthreads();
    for (int c = 0; c < 32; ++c) {
      while (__hip_atomic_load(done0 + b, __ATOMIC_ACQUIRE, __HIP_MEMORY_SCOPE_AGENT)
             < (unsigned)(c + 1))
        __builtin_amdgcn_s_sleep(8);
      // stage 16x256 fp8 h0 chunk -> LDS (rows padded to 272)
      {
        unsigned int v = *(const unsigned int*)(hs8 + (size_t)b * 131072 + (c << 12) + (tid << 2));
        *(unsigned int*)(h0l + (tid >> 6) * 272 + ((tid & 63) << 2)) = v;
      }
      __syncthreads();
      // chunk GEMM: A rows = 16 timesteps (lane lr), B = W_ih1 fp8 from L2
      f32x4 ga0 = (f32x4)0.f, ga1 = (f32x4)0.f, ga2 = (f32x4)0.f, ga3 = (f32x4)0.f;
#pragma unroll
      for (int kc = 0; kc < 2; ++kc) {
        const uint4* ap = (const uint4*)(h0l + lr * 272 + (kc << 7) + (lg << 5));
        uint4 alo = ap[0], ahi = ap[1];
        i32x8 a;
        a[0] = alo.x; a[1] = alo.y; a[2] = alo.z; a[3] = alo.w;
        a[4] = ahi.x; a[5] = ahi.y; a[6] = ahi.z; a[7] = ahi.w;
        const unsigned char* wb = W1p8 + (size_t)hcol * 256 + (kc << 7) + (lg << 5);
#pragma unroll
        for (int g = 0; g < 4; ++g) {
          const uint4* bp = (const uint4*)(wb + (size_t)g * 65536);
          uint4 blo = bp[0], bhi = bp[1];
          i32x8 bv;
          bv[0] = blo.x; bv[1] = blo.y; bv[2] = blo.z; bv[3] = blo.w;
          bv[4] = bhi.x; bv[5] = bhi.y; bv[6] = bhi.z; bv[7] = bhi.w;
          if (g == 0) ga0 = __builtin_amdgcn_mfma_scale_f32_16x16x128_f8f6f4(a, bv, ga0, 0, 0, 0, SCALE_ONE, 0, SCALE_ONE);
          if (g == 1) ga1 = __builtin_amdgcn_mfma_scale_f32_16x16x128_f8f6f4(a, bv, ga1, 0, 0, 0, SCALE_ONE, 0, SCALE_ONE);
          if (g == 2) ga2 = __builtin_amdgcn_mfma_scale_f32_16x16x128_f8f6f4(a, bv, ga2, 0, 0, 0, SCALE_ONE, 0, SCALE_ONE);
          if (g == 3) ga3 = __builtin_amdgcn_mfma_scale_f32_16x16x128_f8f6f4(a, bv, ga3, 0, 0, 0, SCALE_ONE, 0, SCALE_ONE);
        }
      }
      // xp chunk -> LDS bf16, bias folded; C row = 4*lg + reg, col = hcol, gate-interleaved
#pragma unroll
      for (int i = 0; i < 4; ++i) {
        const int row = (lg << 2) + i;
        union { uint2 u; ushort s[4]; } pk;
        pk.s[0] = f2bf(ga0[i] * INV_SCALE + bias[0]);
        pk.s[1] = f2bf(ga1[i] * INV_SCALE + bias[1]);
        pk.s[2] = f2bf(ga2[i] * INV_SCALE + bias[2]);
        pk.s[3] = f2bf(ga3[i] * INV_SCALE + bias[3]);
        *(uint2*)(xpcu + row * 1024 + (hcol << 2)) = pk.u;
      }
      __syncthreads();
      // 16 recurrent steps (R7-verified structure, xp from LDS)
      for (int ts = 0; ts < 16; ++ts) {
        const int t = (c << 4) + ts;
        const unsigned char* hr = hbb + ((t & 1) * 320);
        unsigned char* hw = hbb + (((t & 1) ^ 1) * 320);
        i32x8 af[2];
#pragma unroll
        for (int kc = 0; kc < 2; ++kc) {
          const uint4* p = (const uint4*)(hr + kc * 128 + lg * 32);
          uint4 lo = p[0], hi = p[1];
          i32x8 a;
          a[0] = lo.x; a[1] = lo.y; a[2] = lo.z; a[3] = lo.w;
          a[4] = hi.x; a[5] = hi.y; a[6] = hi.z; a[7] = hi.w;
          af[kc] = a;
        }
        f32x4 acc0 = (f32x4)0.f, acc1 = (f32x4)0.f, acc2 = (f32x4)0.f, acc3 = (f32x4)0.f;
#pragma unroll
        for (int kc = 0; kc < 2; ++kc) {
          acc0 = __builtin_amdgcn_mfma_scale_f32_16x16x128_f8f6f4(af[kc], wf[0][kc], acc0, 0, 0, 0, SCALE_ONE, 0, SCALE_ONE);
          acc1 = __builtin_amdgcn_mfma_scale_f32_16x16x128_f8f6f4(af[kc], wf[1][kc], acc1, 0, 0, 0, SCALE_ONE, 0, SCALE_ONE);
          acc2 = __builtin_amdgcn_mfma_scale_f32_16x16x128_f8f6f4(af[kc], wf[2][kc], acc2, 0, 0, 0, SCALE_ONE, 0, SCALE_ONE);
          acc3 = __builtin_amdgcn_mfma_scale_f32_16x16x128_f8f6f4(af[kc], wf[3][kc], acc3, 0, 0, 0, SCALE_ONE, 0, SCALE_ONE);
        }
        const float xv = bf2f(xpcu[ts * 1024 + (hcol << 2) + lg]);
        const float accsel = (lg & 2) ? ((lg & 1) ? acc3[0] : acc2[0])
                                      : ((lg & 1) ? acc1[0] : acc0[0]);
        const float p = accsel * INV_SCALE + xv;
        const float kk2 = (lg == 2) ? (2.f * LOG2E) : LOG2E;
        const float mm = (lg == 2) ? 2.f : 1.f;
        const float ex = __builtin_amdgcn_exp2f(kk2 * p);
        const float v = 1.f - mm * __builtin_amdgcn_rcpf(ex + 1.f);
        const float sf = __shfl(v, lr + 16);
        const float tg = __shfl(v, lr + 32);
        const float so = __shfl(v, lr + 48);
        cc = sf * cc + v * tg;
        const float e2 = __builtin_amdgcn_exp2f(2.f * LOG2E * cc);
        const float th = 1.f - 2.f * __builtin_amdgcn_rcpf(e2 + 1.f);
        const float h = so * th;
        if (lg == 0) {
          int q = __builtin_amdgcn_cvt_pk_fp8_f32(h * 16.f, h * 16.f, 0, false);
          hw[hcol] = (unsigned char)(q & 0xFF);
          if (t == 511) hf[hcol] = h;
        }
        __syncthreads();
      }
    }
    // fc epilogue
    if (w == 0) {
      float s = 0.f;
#pragma unroll
      for (int j = 0; j < 4; ++j) {
        const int k = j * 64 + l;
        s += hf[k] * fcw[k];
      }
      s += __shfl_xor(s, 1);
      s += __shfl_xor(s, 2);
      s += __shfl_xor(s, 4);
      s += __shfl_xor(s, 8);
      s += __shfl_xor(s, 16);
      s += __shfl_xor(s, 32);
      if (l == 0) out[b] = sigm(s + fcb[0]);
    }
  }
}

// ---------------- launch ----------------
extern "C" void kernel_launch(void* const* d_in, const int* in_sizes, int n_in,
                              void* d_out, int out_size, void* d_ws, size_t ws_size,
                              hipStream_t stream)
{
  const int*   x    = (const int*)d_in[0];
  const float* emb  = (const float*)d_in[1];
  const float* fcw  = (const float*)d_in[2];
  const float* fcb  = (const float*)d_in[3];
  const float* Wih0 = (const float*)d_in[4];
  const float* Whh0 = (const float*)d_in[5];
  const float* bih0 = (const float*)d_in[6];
  const float* bhh0 = (const float*)d_in[7];
  const float* Wih1 = (const float*)d_in[8];
  const float* Whh1 = (const float*)d_in[9];
  const float* bih1 = (const float*)d_in[10];
  const float* bhh1 = (const float*)d_in[11];

  char* ws = (char*)d_ws;
  size_t off = 0;
  auto alloc = [&](size_t bytes) {
    void* p = ws + off;
    off = (off + bytes + 255) & ~(size_t)255;
    return p;
  };
  ushort*        xp_ws  = (ushort*)alloc(65536ull * 1024 * 2);
  unsigned char* hs8    = (unsigned char*)alloc(128ull * 512 * 256);
  ushort*        emb_bf = (ushort*)alloc(32000ull * 128 * 2);
  ushort*        W0p    = (ushort*)alloc(1024ull * 128 * 2);
  unsigned char* W1p8   = (unsigned char*)alloc(1024ull * 256);
  float*         b0p    = (float*)alloc(1024 * 4);
  float*         b1p    = (float*)alloc(1024 * 4);
  int*           idx_ws = (int*)alloc(65536 * 4);
  unsigned int*  done0  = (unsigned int*)alloc(128 * 4);

  prep_kernel<<<512, 256, 0, stream>>>(emb, x, Wih0, Wih1, bih0, bhh0, bih1, bhh1,
                                       emb_bf, idx_ws, W0p, W1p8, b0p, b1p, done0);
  gemm_xp<128, true><<<dim3(512, 8), 256, 0, stream>>>(emb_bf, idx_ws, W0p, b0p, xp_ws);
  mega_scan<<<256, 1024, 0, stream>>>(xp_ws, Whh0, Whh1, W1p8, b1p, hs8, done0,
                                      fcw, fcb, (float*)d_out);
}

// Round 9
// 1073.892 us; speedup vs baseline: 2.9061x; 2.9061x over previous
//
#include <hip/hip_runtime.h>
#include <hip/hip_bf16.h>
#include <stdint.h>

typedef float f32x4 __attribute__((ext_vector_type(4)));
typedef short s16x8 __attribute__((ext_vector_type(8)));
typedef int i32x8 __attribute__((ext_vector_type(8)));

#define INV_SCALE (1.0f / 1024.0f)  // W pre-scaled x64, h x16
#define SCALE_ONE 0x7F7F7F7F        // E8M0 1.0 in every byte
#define LOG2E 1.4426950408889634f

__device__ __forceinline__ float sigm(float x) {
  return __builtin_amdgcn_rcpf(1.f + __builtin_amdgcn_exp2f(-LOG2E * x));
}
__device__ __forceinline__ ushort f2bf(float f) {
  union { float f; uint32_t u; } v; v.f = f;
  return (ushort)((v.u + 0x7FFFu + ((v.u >> 16) & 1)) >> 16);
}
__device__ __forceinline__ float bf2f(ushort b) {
  union { uint32_t u; float f; } v; v.u = ((uint32_t)b) << 16; return v.f;
}

// ---------------- prep: converts + permutes + flag reset ----------------
__global__ __launch_bounds__(256) void prep_kernel(
    const float* __restrict__ emb, const int* __restrict__ x,
    const float* __restrict__ Wih0, const float* __restrict__ Wih1,
    const float* __restrict__ bih0, const float* __restrict__ bhh0,
    const float* __restrict__ bih1, const float* __restrict__ bhh1,
    ushort* __restrict__ emb_bf, int* __restrict__ idx_ws,
    ushort* __restrict__ W0p, ushort* __restrict__ W1pb,
    float* __restrict__ b0p, float* __restrict__ b1r,
    unsigned int* __restrict__ done0)
{
  const int stride = gridDim.x * blockDim.x;
  const int gid = blockIdx.x * blockDim.x + threadIdx.x;
  for (int i = gid; i < 32000 * 128; i += stride) emb_bf[i] = f2bf(emb[i]);
  // idx_ws[t*128+b] = x[b*512+t]
  for (int i = gid; i < 65536; i += stride) idx_ws[i] = x[(i & 127) * 512 + (i >> 7)];
  // W0p[j][k] = Wih0[(j&3)*256 + (j>>2)][k]   (j = hid*4 + gate) bf16 (layer-0 xp GEMM)
  for (int i = gid; i < 1024 * 128; i += stride) {
    int j = i >> 7, k = i & 127;
    int p = ((j & 3) << 8) | (j >> 2);
    W0p[i] = f2bf(Wih0[p * 128 + k]);
  }
  // W1pb: RAW row-major bf16 (row j = gate*256+hid, k over 256) for consumer chunk GEMM
  for (int i = gid; i < 1024 * 256; i += stride) W1pb[i] = f2bf(Wih1[i]);
  for (int i = gid; i < 1024; i += stride) {
    int p = ((i & 3) << 8) | (i >> 2);
    b0p[i] = bih0[p] + bhh0[p];   // gate-interleaved (layer 0)
    b1r[i] = bih1[i] + bhh1[i];   // raw (layer 1)
  }
  for (int i = gid; i < 128; i += stride) done0[i] = 0;  // reset chunk flags each launch
}

// ---------------- wide GEMM for xp0: xp[m][j] = emb[idx[m],:] @ W0p[j,:]^T + b0p[j] ----------------
template <int KD, bool GATHER>
__global__ __launch_bounds__(256) void gemm_xp(
    const ushort* __restrict__ A, const int* __restrict__ idx,
    const ushort* __restrict__ B, const float* __restrict__ bias,
    ushort* __restrict__ out)
{
  __shared__ ushort Al[128 * 72];
  __shared__ ushort Bl[128 * 72];
  const int tid = threadIdx.x;
  const int l = tid & 63, w = tid >> 6;
  const int wm = w >> 1, wn = w & 1;
  const int lr = l & 15, lg = l >> 4;
  const int m0 = blockIdx.x * 128, n0 = blockIdx.y * 128;

  f32x4 acc[4][4];
#pragma unroll
  for (int a = 0; a < 4; ++a)
#pragma unroll
    for (int b = 0; b < 4; ++b) acc[a][b] = (f32x4)0.f;

  const int srow = tid >> 1, sseg = tid & 1;
  for (int kk = 0; kk < KD / 64; ++kk) {
    const int k0 = kk * 64;
    size_t arow = GATHER ? (size_t)idx[m0 + srow] : (size_t)(m0 + srow);
    const uint4* sa = (const uint4*)(A + arow * KD + k0 + sseg * 32);
    uint4* da = (uint4*)(Al + srow * 72 + sseg * 32);
    da[0] = sa[0]; da[1] = sa[1]; da[2] = sa[2]; da[3] = sa[3];
    const uint4* sb = (const uint4*)(B + (size_t)(n0 + srow) * KD + k0 + sseg * 32);
    uint4* db = (uint4*)(Bl + srow * 72 + sseg * 32);
    db[0] = sb[0]; db[1] = sb[1]; db[2] = sb[2]; db[3] = sb[3];
    __syncthreads();
#pragma unroll
    for (int ks = 0; ks < 2; ++ks) {
      s16x8 av[4], bv[4];
#pragma unroll
      for (int mt = 0; mt < 4; ++mt)
        av[mt] = *(const s16x8*)(Al + (wm * 64 + mt * 16 + lr) * 72 + ks * 32 + lg * 8);
#pragma unroll
      for (int nt = 0; nt < 4; ++nt)
        bv[nt] = *(const s16x8*)(Bl + (wn * 64 + nt * 16 + lr) * 72 + ks * 32 + lg * 8);
#pragma unroll
      for (int mt = 0; mt < 4; ++mt)
#pragma unroll
        for (int nt = 0; nt < 4; ++nt)
          acc[mt][nt] = __builtin_amdgcn_mfma_f32_16x16x32_bf16(av[mt], bv[nt], acc[mt][nt], 0, 0, 0);
    }
    __syncthreads();
  }

#pragma unroll
  for (int nt = 0; nt < 4; ++nt) {
    const int colg = n0 + wn * 64 + nt * 16 + lr;
    const float bv = bias[colg];
#pragma unroll
    for (int mt = 0; mt < 4; ++mt) {
#pragma unroll
      for (int i = 0; i < 4; ++i) {
        const int rowg = m0 + wm * 64 + mt * 16 + 4 * lg + i;
        out[(size_t)rowg * 1024 + colg] = f2bf(acc[mt][nt][i] + bv);
      }
    }
  }
}

// ---------------- mega: layer-0 scan (WG 0-127) || layer-1 scan (WG 128-255) ----------------
// Pipeline sync routed ENTIRELY through IF$ via relaxed agent-scope atomics:
//  - producer h(t) published as bf16 pairs (1 relaxed atomic dword store / 2 cols / step)
//  - pre-barrier vmcnt drain orders data before tid0's relaxed flag store (no wbl2)
//  - consumer: tid0-only relaxed poll + s_sleep (no per-poll invalidates), then relaxed
//    atomic dword loads stage the chunk to LDS.
__global__ __launch_bounds__(1024) void mega_scan(
    const ushort* __restrict__ xp0, const float* __restrict__ Whh0,
    const float* __restrict__ Whh1, const ushort* __restrict__ W1pb,
    const float* __restrict__ b1r, uint32_t* __restrict__ hs16,
    unsigned int* __restrict__ done0, const float* __restrict__ fcw,
    const float* __restrict__ fcb, float* __restrict__ out)
{
  __shared__ __align__(16) unsigned char smem[43520];
  uint32_t* h0l = (uint32_t*)smem;              // [16][132] dwords: h0 chunk bf16 (pad 132)
  ushort* xpcu = (ushort*)(smem + 8448);        // [16][1040] bf16 xp chunk (pad 1040)
  unsigned char* hbb = smem + 41728;            // [2][320] h ping-pong fp8
  float* hf = (float*)(smem + 42368);           // [260] final h f32

  const int tid = threadIdx.x;
  const int l = tid & 63, w = tid >> 6;
  const int lr = l & 15, lg = l >> 4;
  const bool is0 = blockIdx.x < 128;
  const int b = is0 ? blockIdx.x : (blockIdx.x - 128);
  const float* Whh = is0 ? Whh0 : Whh1;
  const int hcol = 16 * w + lr;

  // W_hh fragments (fp8 x64): gate s, k-chunk kc; B col = 256*s + hcol, k = kc*128 + lg*32 + j
  i32x8 wf[4][2];
#pragma unroll
  for (int s = 0; s < 4; ++s) {
    const int n = 256 * s + hcol;
#pragma unroll
    for (int kc = 0; kc < 2; ++kc) {
      i32x8 r;
#pragma unroll
      for (int d = 0; d < 8; ++d) {
        const f32x4 v = *(const f32x4*)(Whh + (size_t)n * 256 + kc * 128 + lg * 32 + d * 4);
        int q = __builtin_amdgcn_cvt_pk_fp8_f32(v[0] * 64.f, v[1] * 64.f, 0, false);
        q = __builtin_amdgcn_cvt_pk_fp8_f32(v[2] * 64.f, v[3] * 64.f, q, true);
        r[d] = q;
      }
      wf[s][kc] = r;
    }
  }

  if (tid < 320) hbb[tid] = 0;  // h(-1) = 0 (buffer 0)
  float cc = 0.f;

  if (is0) {
    // ================= layer 0 producer (R7-verified step + IF$ publish) =================
    const ushort* xq0 = xp0 + (size_t)b * 1024 + (hcol << 2);
    uint2 xpv = *(const uint2*)xq0;
    __syncthreads();
    for (int t = 0; t < 512; ++t) {
      const unsigned char* hr = hbb + ((t & 1) * 320);
      unsigned char* hw = hbb + (((t & 1) ^ 1) * 320);
      i32x8 af[2];
#pragma unroll
      for (int kc = 0; kc < 2; ++kc) {
        const uint4* p = (const uint4*)(hr + kc * 128 + lg * 32);
        uint4 lo = p[0], hi = p[1];
        i32x8 a;
        a[0] = lo.x; a[1] = lo.y; a[2] = lo.z; a[3] = lo.w;
        a[4] = hi.x; a[5] = hi.y; a[6] = hi.z; a[7] = hi.w;
        af[kc] = a;
      }
      f32x4 acc0 = (f32x4)0.f, acc1 = (f32x4)0.f, acc2 = (f32x4)0.f, acc3 = (f32x4)0.f;
#pragma unroll
      for (int kc = 0; kc < 2; ++kc) {
        acc0 = __builtin_amdgcn_mfma_scale_f32_16x16x128_f8f6f4(af[kc], wf[0][kc], acc0, 0, 0, 0, SCALE_ONE, 0, SCALE_ONE);
        acc1 = __builtin_amdgcn_mfma_scale_f32_16x16x128_f8f6f4(af[kc], wf[1][kc], acc1, 0, 0, 0, SCALE_ONE, 0, SCALE_ONE);
        acc2 = __builtin_amdgcn_mfma_scale_f32_16x16x128_f8f6f4(af[kc], wf[2][kc], acc2, 0, 0, 0, SCALE_ONE, 0, SCALE_ONE);
        acc3 = __builtin_amdgcn_mfma_scale_f32_16x16x128_f8f6f4(af[kc], wf[3][kc], acc3, 0, 0, 0, SCALE_ONE, 0, SCALE_ONE);
      }
      uint2 xpn;
      if (t < 511) xpn = *(const uint2*)(xq0 + (size_t)(t + 1) * 131072);
      // gate phase: lg-specialized nonlinearity, shuffle-combined into lg0
      const uint word = (lg & 2) ? xpv.y : xpv.x;
      const uint h16 = (lg & 1) ? (word >> 16) : (word & 0xFFFFu);
      union { uint32_t u; float f; } xf; xf.u = h16 << 16;
      const float accsel = (lg & 2) ? ((lg & 1) ? acc3[0] : acc2[0])
                                    : ((lg & 1) ? acc1[0] : acc0[0]);
      const float p = accsel * INV_SCALE + xf.f;
      const float kk2 = (lg == 2) ? (2.f * LOG2E) : LOG2E;
      const float mm = (lg == 2) ? 2.f : 1.f;
      const float ex = __builtin_amdgcn_exp2f(kk2 * p);
      const float v = 1.f - mm * __builtin_amdgcn_rcpf(ex + 1.f);
      const float sf = __shfl(v, lr + 16);
      const float tg = __shfl(v, lr + 32);
      const float so = __shfl(v, lr + 48);
      cc = sf * cc + v * tg;
      const float e2 = __builtin_amdgcn_exp2f(2.f * LOG2E * cc);
      const float th = 1.f - 2.f * __builtin_amdgcn_rcpf(e2 + 1.f);
      const float h = so * th;
      if (lg == 0) {
        int q = __builtin_amdgcn_cvt_pk_fp8_f32(h * 16.f, h * 16.f, 0, false);
        hw[hcol] = (unsigned char)(q & 0xFF);
        const ushort v16 = f2bf(h);
        const int pv = __shfl((int)(unsigned)v16, l ^ 1);
        if ((l & 1) == 0) {
          const uint32_t dw = (uint32_t)v16 | ((uint32_t)(unsigned short)pv << 16);
          __hip_atomic_store(hs16 + ((size_t)b * 512 + t) * 128 + (hcol >> 1), dw,
                             __ATOMIC_RELAXED, __HIP_MEMORY_SCOPE_AGENT);
        }
      }
      xpv = xpn;
      __syncthreads();  // per-wave vmcnt drain => chunk data at IF$ before flag
      if ((t & 15) == 15 && tid == 0)
        __hip_atomic_store(done0 + b, (unsigned)((t >> 4) + 1),
                           __ATOMIC_RELAXED, __HIP_MEMORY_SCOPE_AGENT);
    }
  } else {
    // ================= layer 1 consumer: chunk GEMM (bf16, M=16 timesteps) + recurrence =================
    const float bias0 = b1r[hcol], bias1 = b1r[256 + hcol];
    const float bias2 = b1r[512 + hcol], bias3 = b1r[768 + hcol];
    __syncthreads();
    for (int c = 0; c < 32; ++c) {
      if (tid == 0) {
        while (__hip_atomic_load(done0 + b, __ATOMIC_RELAXED, __HIP_MEMORY_SCOPE_AGENT)
               < (unsigned)(c + 1))
          __builtin_amdgcn_s_sleep(2);
      }
      __syncthreads();
      // stage 16x256 bf16 h0 chunk -> LDS (dword rows padded to 132)
#pragma unroll
      for (int it = 0; it < 2; ++it) {
        const int i = tid + it * 1024;
        const int r = i >> 7, kd = i & 127;
        const uint32_t v = __hip_atomic_load(
            hs16 + ((size_t)b * 512 + (c << 4) + r) * 128 + kd,
            __ATOMIC_RELAXED, __HIP_MEMORY_SCOPE_AGENT);
        h0l[r * 132 + kd] = v;
      }
      __syncthreads();
      // chunk GEMM: A rows = 16 timesteps, bf16 16x16x32; B = W1pb raw from L2
      f32x4 ga0 = (f32x4)0.f, ga1 = (f32x4)0.f, ga2 = (f32x4)0.f, ga3 = (f32x4)0.f;
#pragma unroll
      for (int kc = 0; kc < 8; ++kc) {
        const s16x8 av = *(const s16x8*)((const unsigned char*)h0l + lr * 528 + kc * 64 + lg * 16);
        const size_t bko = (size_t)kc * 32 + lg * 8;
        const s16x8 bv0 = *(const s16x8*)(W1pb + (size_t)(hcol) * 256 + bko);
        const s16x8 bv1 = *(const s16x8*)(W1pb + (size_t)(256 + hcol) * 256 + bko);
        const s16x8 bv2 = *(const s16x8*)(W1pb + (size_t)(512 + hcol) * 256 + bko);
        const s16x8 bv3 = *(const s16x8*)(W1pb + (size_t)(768 + hcol) * 256 + bko);
        ga0 = __builtin_amdgcn_mfma_f32_16x16x32_bf16(av, bv0, ga0, 0, 0, 0);
        ga1 = __builtin_amdgcn_mfma_f32_16x16x32_bf16(av, bv1, ga1, 0, 0, 0);
        ga2 = __builtin_amdgcn_mfma_f32_16x16x32_bf16(av, bv2, ga2, 0, 0, 0);
        ga3 = __builtin_amdgcn_mfma_f32_16x16x32_bf16(av, bv3, ga3, 0, 0, 0);
      }
      // xp chunk -> LDS bf16 with bias; C row = 4*lg+i (timestep), col = gate*256 + hcol
#pragma unroll
      for (int i = 0; i < 4; ++i) {
        const int row = (lg << 2) + i;
        xpcu[row * 1040 + hcol]       = f2bf(ga0[i] + bias0);
        xpcu[row * 1040 + 256 + hcol] = f2bf(ga1[i] + bias1);
        xpcu[row * 1040 + 512 + hcol] = f2bf(ga2[i] + bias2);
        xpcu[row * 1040 + 768 + hcol] = f2bf(ga3[i] + bias3);
      }
      __syncthreads();
      // 16 recurrent steps (R7-verified structure; xp from LDS, raw gate order = lg*256+hcol)
      for (int ts = 0; ts < 16; ++ts) {
        const int t = (c << 4) + ts;
        const unsigned char* hr = hbb + ((t & 1) * 320);
        unsigned char* hw = hbb + (((t & 1) ^ 1) * 320);
        i32x8 af[2];
#pragma unroll
        for (int kc = 0; kc < 2; ++kc) {
          const uint4* p = (const uint4*)(hr + kc * 128 + lg * 32);
          uint4 lo = p[0], hi = p[1];
          i32x8 a;
          a[0] = lo.x; a[1] = lo.y; a[2] = lo.z; a[3] = lo.w;
          a[4] = hi.x; a[5] = hi.y; a[6] = hi.z; a[7] = hi.w;
          af[kc] = a;
        }
        f32x4 acc0 = (f32x4)0.f, acc1 = (f32x4)0.f, acc2 = (f32x4)0.f, acc3 = (f32x4)0.f;
#pragma unroll
        for (int kc = 0; kc < 2; ++kc) {
          acc0 = __builtin_amdgcn_mfma_scale_f32_16x16x128_f8f6f4(af[kc], wf[0][kc], acc0, 0, 0, 0, SCALE_ONE, 0, SCALE_ONE);
          acc1 = __builtin_amdgcn_mfma_scale_f32_16x16x128_f8f6f4(af[kc], wf[1][kc], acc1, 0, 0, 0, SCALE_ONE, 0, SCALE_ONE);
          acc2 = __builtin_amdgcn_mfma_scale_f32_16x16x128_f8f6f4(af[kc], wf[2][kc], acc2, 0, 0, 0, SCALE_ONE, 0, SCALE_ONE);
          acc3 = __builtin_amdgcn_mfma_scale_f32_16x16x128_f8f6f4(af[kc], wf[3][kc], acc3, 0, 0, 0, SCALE_ONE, 0, SCALE_ONE);
        }
        const float xv = bf2f(xpcu[ts * 1040 + (lg << 8) + hcol]);
        const float accsel = (lg & 2) ? ((lg & 1) ? acc3[0] : acc2[0])
                                      : ((lg & 1) ? acc1[0] : acc0[0]);
        const float p = accsel * INV_SCALE + xv;
        const float kk2 = (lg == 2) ? (2.f * LOG2E) : LOG2E;
        const float mm = (lg == 2) ? 2.f : 1.f;
        const float ex = __builtin_amdgcn_exp2f(kk2 * p);
        const float v = 1.f - mm * __builtin_amdgcn_rcpf(ex + 1.f);
        const float sf = __shfl(v, lr + 16);
        const float tg = __shfl(v, lr + 32);
        const float so = __shfl(v, lr + 48);
        cc = sf * cc + v * tg;
        const float e2 = __builtin_amdgcn_exp2f(2.f * LOG2E * cc);
        const float th = 1.f - 2.f * __builtin_amdgcn_rcpf(e2 + 1.f);
        const float h = so * th;
        if (lg == 0) {
          int q = __builtin_amdgcn_cvt_pk_fp8_f32(h * 16.f, h * 16.f, 0, false);
          hw[hcol] = (unsigned char)(q & 0xFF);
          if (t == 511) hf[hcol] = h;
        }
        __syncthreads();
      }
    }
    // fc epilogue
    if (w == 0) {
      float s = 0.f;
#pragma unroll
      for (int j = 0; j < 4; ++j) {
        const int k = j * 64 + l;
        s += hf[k] * fcw[k];
      }
      s += __shfl_xor(s, 1);
      s += __shfl_xor(s, 2);
      s += __shfl_xor(s, 4);
      s += __shfl_xor(s, 8);
      s += __shfl_xor(s, 16);
      s += __shfl_xor(s, 32);
      if (l == 0) out[b] = sigm(s + fcb[0]);
    }
  }
}

// ---------------- launch ----------------
extern "C" void kernel_launch(void* const* d_in, const int* in_sizes, int n_in,
                              void* d_out, int out_size, void* d_ws, size_t ws_size,
                              hipStream_t stream)
{
  const int*   x    = (const int*)d_in[0];
  const float* emb  = (const float*)d_in[1];
  const float* fcw  = (const float*)d_in[2];
  const float* fcb  = (const float*)d_in[3];
  const float* Wih0 = (const float*)d_in[4];
  const float* Whh0 = (const float*)d_in[5];
  const float* bih0 = (const float*)d_in[6];
  const float* bhh0 = (const float*)d_in[7];
  const float* Wih1 = (const float*)d_in[8];
  const float* Whh1 = (const float*)d_in[9];
  const float* bih1 = (const float*)d_in[10];
  const float* bhh1 = (const float*)d_in[11];

  char* ws = (char*)d_ws;
  size_t off = 0;
  auto alloc = [&](size_t bytes) {
    void* p = ws + off;
    off = (off + bytes + 255) & ~(size_t)255;
    return p;
  };
  ushort*        xp_ws  = (ushort*)alloc(65536ull * 1024 * 2);
  uint32_t*      hs16   = (uint32_t*)alloc(128ull * 512 * 128 * 4);
  ushort*        emb_bf = (ushort*)alloc(32000ull * 128 * 2);
  ushort*        W0p    = (ushort*)alloc(1024ull * 128 * 2);
  ushort*        W1pb   = (ushort*)alloc(1024ull * 256 * 2);
  float*         b0p    = (float*)alloc(1024 * 4);
  float*         b1r    = (float*)alloc(1024 * 4);
  int*           idx_ws = (int*)alloc(65536 * 4);
  unsigned int*  done0  = (unsigned int*)alloc(128 * 4);

  prep_kernel<<<512, 256, 0, stream>>>(emb, x, Wih0, Wih1, bih0, bhh0, bih1, bhh1,
                                       emb_bf, idx_ws, W0p, W1pb, b0p, b1r, done0);
  gemm_xp<128, true><<<dim3(512, 8), 256, 0, stream>>>(emb_bf, idx_ws, W0p, b0p, xp_ws);
  mega_scan<<<256, 1024, 0, stream>>>(xp_ws, Whh0, Whh1, W1pb, b1r, hs16, done0,
                                      fcw, fcb, (float*)d_out);
}

// Round 10
// 953.129 us; speedup vs baseline: 3.2744x; 1.1267x over previous
//
#include <hip/hip_runtime.h>
#include <hip/hip_bf16.h>
#include <stdint.h>

typedef float f32x4 __attribute__((ext_vector_type(4)));
typedef short s16x8 __attribute__((ext_vector_type(8)));
typedef int i32x8 __attribute__((ext_vector_type(8)));

#define INV_SCALE (1.0f / 1024.0f)  // W pre-scaled x64, h x16
#define SCALE_ONE 0x7F7F7F7F        // E8M0 1.0 in every byte
#define LOG2E 1.4426950408889634f

__device__ __forceinline__ float sigm(float x) {
  return __builtin_amdgcn_rcpf(1.f + __builtin_amdgcn_exp2f(-LOG2E * x));
}
__device__ __forceinline__ ushort f2bf(float f) {
  union { float f; uint32_t u; } v; v.f = f;
  return (ushort)((v.u + 0x7FFFu + ((v.u >> 16) & 1)) >> 16);
}
__device__ __forceinline__ float bf2f(ushort b) {
  union { uint32_t u; float f; } v; v.u = ((uint32_t)b) << 16; return v.f;
}

// ---------------- prep: converts + permutes + flag reset ----------------
__global__ __launch_bounds__(256) void prep_kernel(
    const float* __restrict__ emb, const int* __restrict__ x,
    const float* __restrict__ Wih0, const float* __restrict__ Wih1,
    const float* __restrict__ bih0, const float* __restrict__ bhh0,
    const float* __restrict__ bih1, const float* __restrict__ bhh1,
    ushort* __restrict__ emb_bf, int* __restrict__ idx_ws,
    ushort* __restrict__ W0p, unsigned char* __restrict__ W1p8,
    float* __restrict__ b0p, float* __restrict__ b1p,
    unsigned int* __restrict__ done0)
{
  const int stride = gridDim.x * blockDim.x;
  const int gid = blockIdx.x * blockDim.x + threadIdx.x;
  for (int i = gid; i < 32000 * 128; i += stride) emb_bf[i] = f2bf(emb[i]);
  // idx_ws[t*128+b] = x[b*512+t]
  for (int i = gid; i < 65536; i += stride) idx_ws[i] = x[(i & 127) * 512 + (i >> 7)];
  // W0p[j][k] = Wih0[(j&3)*256 + (j>>2)][k]   (j = hid*4 + gate) bf16 (layer-0 xp GEMM)
  for (int i = gid; i < 1024 * 128; i += stride) {
    int j = i >> 7, k = i & 127;
    int p = ((j & 3) << 8) | (j >> 2);
    W0p[i] = f2bf(Wih0[p * 128 + k]);
  }
  // W1p8: RAW layout (row = gate*256+hid), fp8 e4m3 x64 (consumer chunk GEMM, R8-proven)
  for (int i = gid; i < 131072; i += stride) {
    int q = __builtin_amdgcn_cvt_pk_fp8_f32(Wih1[2 * i] * 64.f, Wih1[2 * i + 1] * 64.f, 0, false);
    ((ushort*)W1p8)[i] = (ushort)(q & 0xFFFF);
  }
  for (int i = gid; i < 1024; i += stride) {
    int p = ((i & 3) << 8) | (i >> 2);
    b0p[i] = bih0[p] + bhh0[p];   // gate-interleaved (layer 0 xp GEMM)
    b1p[i] = bih1[p] + bhh1[p];   // gate-interleaved (consumer epilogue)
  }
  for (int i = gid; i < 128; i += stride) done0[i] = 0;  // reset chunk flags each launch
}

// ---------------- wide GEMM for xp0: xp[m][j] = emb[idx[m],:] @ W0p[j,:]^T + b0p[j] ----------------
template <int KD, bool GATHER>
__global__ __launch_bounds__(256) void gemm_xp(
    const ushort* __restrict__ A, const int* __restrict__ idx,
    const ushort* __restrict__ B, const float* __restrict__ bias,
    ushort* __restrict__ out)
{
  __shared__ ushort Al[128 * 72];
  __shared__ ushort Bl[128 * 72];
  const int tid = threadIdx.x;
  const int l = tid & 63, w = tid >> 6;
  const int wm = w >> 1, wn = w & 1;
  const int lr = l & 15, lg = l >> 4;
  const int m0 = blockIdx.x * 128, n0 = blockIdx.y * 128;

  f32x4 acc[4][4];
#pragma unroll
  for (int a = 0; a < 4; ++a)
#pragma unroll
    for (int b = 0; b < 4; ++b) acc[a][b] = (f32x4)0.f;

  const int srow = tid >> 1, sseg = tid & 1;
  for (int kk = 0; kk < KD / 64; ++kk) {
    const int k0 = kk * 64;
    size_t arow = GATHER ? (size_t)idx[m0 + srow] : (size_t)(m0 + srow);
    const uint4* sa = (const uint4*)(A + arow * KD + k0 + sseg * 32);
    uint4* da = (uint4*)(Al + srow * 72 + sseg * 32);
    da[0] = sa[0]; da[1] = sa[1]; da[2] = sa[2]; da[3] = sa[3];
    const uint4* sb = (const uint4*)(B + (size_t)(n0 + srow) * KD + k0 + sseg * 32);
    uint4* db = (uint4*)(Bl + srow * 72 + sseg * 32);
    db[0] = sb[0]; db[1] = sb[1]; db[2] = sb[2]; db[3] = sb[3];
    __syncthreads();
#pragma unroll
    for (int ks = 0; ks < 2; ++ks) {
      s16x8 av[4], bv[4];
#pragma unroll
      for (int mt = 0; mt < 4; ++mt)
        av[mt] = *(const s16x8*)(Al + (wm * 64 + mt * 16 + lr) * 72 + ks * 32 + lg * 8);
#pragma unroll
      for (int nt = 0; nt < 4; ++nt)
        bv[nt] = *(const s16x8*)(Bl + (wn * 64 + nt * 16 + lr) * 72 + ks * 32 + lg * 8);
#pragma unroll
      for (int mt = 0; mt < 4; ++mt)
#pragma unroll
        for (int nt = 0; nt < 4; ++nt)
          acc[mt][nt] = __builtin_amdgcn_mfma_f32_16x16x32_bf16(av[mt], bv[nt], acc[mt][nt], 0, 0, 0);
    }
    __syncthreads();
  }

#pragma unroll
  for (int nt = 0; nt < 4; ++nt) {
    const int colg = n0 + wn * 64 + nt * 16 + lr;
    const float bv = bias[colg];
#pragma unroll
    for (int mt = 0; mt < 4; ++mt) {
#pragma unroll
      for (int i = 0; i < 4; ++i) {
        const int rowg = m0 + wm * 64 + mt * 16 + 4 * lg + i;
        // non-temporal: xp0 is streamed once by the producers; keep it out of L2
        __builtin_nontemporal_store(f2bf(acc[mt][nt][i] + bv), &out[(size_t)rowg * 1024 + colg]);
      }
    }
  }
}

// ---------------- mega: layer-0 scan (WG 0-127) || layer-1 scan (WG 128-255) ----------------
// Sync through IF$ via relaxed agent-scope atomics (R9-proven); consumer GEMM = R8-proven
// fp8 path (W1p8 RAW fp8 x64 + h0 fp8 staged in LDS). xp0 producer loads are non-temporal
// so W1p8 stays L2-resident for the consumers.
__global__ __launch_bounds__(1024) void mega_scan(
    const ushort* __restrict__ xp0, const float* __restrict__ Whh0,
    const float* __restrict__ Whh1, const unsigned char* __restrict__ W1p8,
    const float* __restrict__ b1p, uint32_t* __restrict__ hs8u,
    unsigned int* __restrict__ done0, const float* __restrict__ fcw,
    const float* __restrict__ fcb, float* __restrict__ out)
{
  __shared__ __align__(16) unsigned char smem[38800];
  ushort* xpcu = (ushort*)smem;                 // [16][1024] bf16 xp chunk (layer 1)
  unsigned char* h0l = smem + 32768;            // [16][272]  fp8 h0 chunk stage
  unsigned char* hbb = smem + 37120;            // [2][320]   h ping-pong fp8
  float* hf = (float*)(smem + 37760);           // [260]      final h f32

  const int tid = threadIdx.x;
  const int l = tid & 63, w = tid >> 6;
  const int lr = l & 15, lg = l >> 4;
  const bool is0 = blockIdx.x < 128;
  const int b = is0 ? blockIdx.x : (blockIdx.x - 128);
  const float* Whh = is0 ? Whh0 : Whh1;
  const int hcol = 16 * w + lr;

  // W_hh fragments (fp8 x64): gate s, k-chunk kc; B col = 256*s + hcol, k = kc*128 + lg*32 + j
  i32x8 wf[4][2];
#pragma unroll
  for (int s = 0; s < 4; ++s) {
    const int n = 256 * s + hcol;
#pragma unroll
    for (int kc = 0; kc < 2; ++kc) {
      i32x8 r;
#pragma unroll
      for (int d = 0; d < 8; ++d) {
        const f32x4 v = *(const f32x4*)(Whh + (size_t)n * 256 + kc * 128 + lg * 32 + d * 4);
        int q = __builtin_amdgcn_cvt_pk_fp8_f32(v[0] * 64.f, v[1] * 64.f, 0, false);
        q = __builtin_amdgcn_cvt_pk_fp8_f32(v[2] * 64.f, v[3] * 64.f, q, true);
        r[d] = q;
      }
      wf[s][kc] = r;
    }
  }

  if (tid < 320) hbb[tid] = 0;  // h(-1) = 0 (buffer 0)
  float cc = 0.f;

  if (is0) {
    // ================= layer 0 producer (R7 step + packed-fp8 IF$ publish) =================
    const ushort* xq0 = xp0 + (size_t)b * 1024 + (hcol << 2);
    uint2 xpv;
    {
      unsigned long long q8 = __builtin_nontemporal_load((const unsigned long long*)xq0);
      xpv.x = (uint32_t)q8; xpv.y = (uint32_t)(q8 >> 32);
    }
    __syncthreads();
    for (int t = 0; t < 512; ++t) {
      const unsigned char* hr = hbb + ((t & 1) * 320);
      unsigned char* hw = hbb + (((t & 1) ^ 1) * 320);
      i32x8 af[2];
#pragma unroll
      for (int kc = 0; kc < 2; ++kc) {
        const uint4* p = (const uint4*)(hr + kc * 128 + lg * 32);
        uint4 lo = p[0], hi = p[1];
        i32x8 a;
        a[0] = lo.x; a[1] = lo.y; a[2] = lo.z; a[3] = lo.w;
        a[4] = hi.x; a[5] = hi.y; a[6] = hi.z; a[7] = hi.w;
        af[kc] = a;
      }
      f32x4 acc0 = (f32x4)0.f, acc1 = (f32x4)0.f, acc2 = (f32x4)0.f, acc3 = (f32x4)0.f;
#pragma unroll
      for (int kc = 0; kc < 2; ++kc) {
        acc0 = __builtin_amdgcn_mfma_scale_f32_16x16x128_f8f6f4(af[kc], wf[0][kc], acc0, 0, 0, 0, SCALE_ONE, 0, SCALE_ONE);
        acc1 = __builtin_amdgcn_mfma_scale_f32_16x16x128_f8f6f4(af[kc], wf[1][kc], acc1, 0, 0, 0, SCALE_ONE, 0, SCALE_ONE);
        acc2 = __builtin_amdgcn_mfma_scale_f32_16x16x128_f8f6f4(af[kc], wf[2][kc], acc2, 0, 0, 0, SCALE_ONE, 0, SCALE_ONE);
        acc3 = __builtin_amdgcn_mfma_scale_f32_16x16x128_f8f6f4(af[kc], wf[3][kc], acc3, 0, 0, 0, SCALE_ONE, 0, SCALE_ONE);
      }
      uint2 xpn;
      if (t < 511) {
        unsigned long long q8 = __builtin_nontemporal_load(
            (const unsigned long long*)(xq0 + (size_t)(t + 1) * 131072));
        xpn.x = (uint32_t)q8; xpn.y = (uint32_t)(q8 >> 32);
      }
      // gate phase: lg-specialized nonlinearity, shuffle-combined into lg0
      const uint word = (lg & 2) ? xpv.y : xpv.x;
      const uint h16 = (lg & 1) ? (word >> 16) : (word & 0xFFFFu);
      union { uint32_t u; float f; } xf; xf.u = h16 << 16;
      const float accsel = (lg & 2) ? ((lg & 1) ? acc3[0] : acc2[0])
                                    : ((lg & 1) ? acc1[0] : acc0[0]);
      const float p = accsel * INV_SCALE + xf.f;
      const float kk2 = (lg == 2) ? (2.f * LOG2E) : LOG2E;
      const float mm = (lg == 2) ? 2.f : 1.f;
      const float ex = __builtin_amdgcn_exp2f(kk2 * p);
      const float v = 1.f - mm * __builtin_amdgcn_rcpf(ex + 1.f);
      const float sf = __shfl(v, lr + 16);
      const float tg = __shfl(v, lr + 32);
      const float so = __shfl(v, lr + 48);
      cc = sf * cc + v * tg;
      const float e2 = __builtin_amdgcn_exp2f(2.f * LOG2E * cc);
      const float th = 1.f - 2.f * __builtin_amdgcn_rcpf(e2 + 1.f);
      const float h = so * th;
      if (lg == 0) {
        int q = __builtin_amdgcn_cvt_pk_fp8_f32(h * 16.f, h * 16.f, 0, false);
        hw[hcol] = (unsigned char)(q & 0xFF);
        // pack 4 fp8 bytes (cols 16w+4i..+3) into one dword via 2 shfls (lanes 0..15 active)
        uint v8 = (uint)(q & 0xFF);
        uint v1 = (uint)__shfl((int)v8, (int)(l ^ 1));
        uint u = v8 | (v1 << 8);
        uint u2 = (uint)__shfl((int)u, (int)(l ^ 2));
        if ((l & 3) == 0) {
          uint dw = u | (u2 << 16);
          __hip_atomic_store(hs8u + ((size_t)b * 512 + t) * 64 + 4 * w + (l >> 2), dw,
                             __ATOMIC_RELAXED, __HIP_MEMORY_SCOPE_AGENT);
        }
      }
      xpv = xpn;
      __syncthreads();  // vmcnt drain: publish atomics complete before flag
      if ((t & 15) == 15 && tid == 0)
        __hip_atomic_store(done0 + b, (unsigned)((t >> 4) + 1),
                           __ATOMIC_RELAXED, __HIP_MEMORY_SCOPE_AGENT);
    }
  } else {
    // ================= layer 1 consumer: R8-proven fp8 chunk GEMM + recurrence =================
    const f32x4 bias = *(const f32x4*)(b1p + (hcol << 2));
    __syncthreads();
    for (int c = 0; c < 32; ++c) {
      if (tid == 0) {
        while (__hip_atomic_load(done0 + b, __ATOMIC_RELAXED, __HIP_MEMORY_SCOPE_AGENT)
               < (unsigned)(c + 1))
          __builtin_amdgcn_s_sleep(2);
      }
      __syncthreads();
      // stage 16x256 fp8 h0 chunk -> LDS (rows padded to 272), relaxed atomic dword loads
      {
        const int r = tid >> 6, kd = tid & 63;
        const uint32_t v = __hip_atomic_load(
            hs8u + ((size_t)b * 512 + (c << 4) + r) * 64 + kd,
            __ATOMIC_RELAXED, __HIP_MEMORY_SCOPE_AGENT);
        *(uint32_t*)(h0l + r * 272 + (kd << 2)) = v;
      }
      __syncthreads();
      // chunk GEMM: A rows = 16 timesteps (lane lr), B = W_ih1 fp8 from L2
      f32x4 ga0 = (f32x4)0.f, ga1 = (f32x4)0.f, ga2 = (f32x4)0.f, ga3 = (f32x4)0.f;
#pragma unroll
      for (int kc = 0; kc < 2; ++kc) {
        const uint4* ap = (const uint4*)(h0l + lr * 272 + (kc << 7) + (lg << 5));
        uint4 alo = ap[0], ahi = ap[1];
        i32x8 a;
        a[0] = alo.x; a[1] = alo.y; a[2] = alo.z; a[3] = alo.w;
        a[4] = ahi.x; a[5] = ahi.y; a[6] = ahi.z; a[7] = ahi.w;
        const unsigned char* wb = W1p8 + (size_t)hcol * 256 + (kc << 7) + (lg << 5);
#pragma unroll
        for (int g = 0; g < 4; ++g) {
          const uint4* bp = (const uint4*)(wb + (size_t)g * 65536);
          uint4 blo = bp[0], bhi = bp[1];
          i32x8 bv;
          bv[0] = blo.x; bv[1] = blo.y; bv[2] = blo.z; bv[3] = blo.w;
          bv[4] = bhi.x; bv[5] = bhi.y; bv[6] = bhi.z; bv[7] = bhi.w;
          if (g == 0) ga0 = __builtin_amdgcn_mfma_scale_f32_16x16x128_f8f6f4(a, bv, ga0, 0, 0, 0, SCALE_ONE, 0, SCALE_ONE);
          if (g == 1) ga1 = __builtin_amdgcn_mfma_scale_f32_16x16x128_f8f6f4(a, bv, ga1, 0, 0, 0, SCALE_ONE, 0, SCALE_ONE);
          if (g == 2) ga2 = __builtin_amdgcn_mfma_scale_f32_16x16x128_f8f6f4(a, bv, ga2, 0, 0, 0, SCALE_ONE, 0, SCALE_ONE);
          if (g == 3) ga3 = __builtin_amdgcn_mfma_scale_f32_16x16x128_f8f6f4(a, bv, ga3, 0, 0, 0, SCALE_ONE, 0, SCALE_ONE);
        }
      }
      // xp chunk -> LDS bf16, bias folded; C row = 4*lg + i (timestep), gate-interleaved cols
#pragma unroll
      for (int i = 0; i < 4; ++i) {
        const int row = (lg << 2) + i;
        union { uint2 u; ushort s[4]; } pk;
        pk.s[0] = f2bf(ga0[i] * INV_SCALE + bias[0]);
        pk.s[1] = f2bf(ga1[i] * INV_SCALE + bias[1]);
        pk.s[2] = f2bf(ga2[i] * INV_SCALE + bias[2]);
        pk.s[3] = f2bf(ga3[i] * INV_SCALE + bias[3]);
        *(uint2*)(xpcu + row * 1024 + (hcol << 2)) = pk.u;
      }
      __syncthreads();
      // 16 recurrent steps (R7-verified structure, xp from LDS gate-interleaved)
      for (int ts = 0; ts < 16; ++ts) {
        const int t = (c << 4) + ts;
        const unsigned char* hr = hbb + ((t & 1) * 320);
        unsigned char* hw = hbb + (((t & 1) ^ 1) * 320);
        i32x8 af[2];
#pragma unroll
        for (int kc = 0; kc < 2; ++kc) {
          const uint4* p = (const uint4*)(hr + kc * 128 + lg * 32);
          uint4 lo = p[0], hi = p[1];
          i32x8 a;
          a[0] = lo.x; a[1] = lo.y; a[2] = lo.z; a[3] = lo.w;
          a[4] = hi.x; a[5] = hi.y; a[6] = hi.z; a[7] = hi.w;
          af[kc] = a;
        }
        f32x4 acc0 = (f32x4)0.f, acc1 = (f32x4)0.f, acc2 = (f32x4)0.f, acc3 = (f32x4)0.f;
#pragma unroll
        for (int kc = 0; kc < 2; ++kc) {
          acc0 = __builtin_amdgcn_mfma_scale_f32_16x16x128_f8f6f4(af[kc], wf[0][kc], acc0, 0, 0, 0, SCALE_ONE, 0, SCALE_ONE);
          acc1 = __builtin_amdgcn_mfma_scale_f32_16x16x128_f8f6f4(af[kc], wf[1][kc], acc1, 0, 0, 0, SCALE_ONE, 0, SCALE_ONE);
          acc2 = __builtin_amdgcn_mfma_scale_f32_16x16x128_f8f6f4(af[kc], wf[2][kc], acc2, 0, 0, 0, SCALE_ONE, 0, SCALE_ONE);
          acc3 = __builtin_amdgcn_mfma_scale_f32_16x16x128_f8f6f4(af[kc], wf[3][kc], acc3, 0, 0, 0, SCALE_ONE, 0, SCALE_ONE);
        }
        const float xv = bf2f(xpcu[ts * 1024 + (hcol << 2) + lg]);
        const float accsel = (lg & 2) ? ((lg & 1) ? acc3[0] : acc2[0])
                                      : ((lg & 1) ? acc1[0] : acc0[0]);
        const float p = accsel * INV_SCALE + xv;
        const float kk2 = (lg == 2) ? (2.f * LOG2E) : LOG2E;
        const float mm = (lg == 2) ? 2.f : 1.f;
        const float ex = __builtin_amdgcn_exp2f(kk2 * p);
        const float v = 1.f - mm * __builtin_amdgcn_rcpf(ex + 1.f);
        const float sf = __shfl(v, lr + 16);
        const float tg = __shfl(v, lr + 32);
        const float so = __shfl(v, lr + 48);
        cc = sf * cc + v * tg;
        const float e2 = __builtin_amdgcn_exp2f(2.f * LOG2E * cc);
        const float th = 1.f - 2.f * __builtin_amdgcn_rcpf(e2 + 1.f);
        const float h = so * th;
        if (lg == 0) {
          int q = __builtin_amdgcn_cvt_pk_fp8_f32(h * 16.f, h * 16.f, 0, false);
          hw[hcol] = (unsigned char)(q & 0xFF);
          if (t == 511) hf[hcol] = h;
        }
        __syncthreads();
      }
    }
    // fc epilogue
    if (w == 0) {
      float s = 0.f;
#pragma unroll
      for (int j = 0; j < 4; ++j) {
        const int k = j * 64 + l;
        s += hf[k] * fcw[k];
      }
      s += __shfl_xor(s, 1);
      s += __shfl_xor(s, 2);
      s += __shfl_xor(s, 4);
      s += __shfl_xor(s, 8);
      s += __shfl_xor(s, 16);
      s += __shfl_xor(s, 32);
      if (l == 0) out[b] = sigm(s + fcb[0]);
    }
  }
}

// ---------------- launch ----------------
extern "C" void kernel_launch(void* const* d_in, const int* in_sizes, int n_in,
                              void* d_out, int out_size, void* d_ws, size_t ws_size,
                              hipStream_t stream)
{
  const int*   x    = (const int*)d_in[0];
  const float* emb  = (const float*)d_in[1];
  const float* fcw  = (const float*)d_in[2];
  const float* fcb  = (const float*)d_in[3];
  const float* Wih0 = (const float*)d_in[4];
  const float* Whh0 = (const float*)d_in[5];
  const float* bih0 = (const float*)d_in[6];
  const float* bhh0 = (const float*)d_in[7];
  const float* Wih1 = (const float*)d_in[8];
  const float* Whh1 = (const float*)d_in[9];
  const float* bih1 = (const float*)d_in[10];
  const float* bhh1 = (const float*)d_in[11];

  char* ws = (char*)d_ws;
  size_t off = 0;
  auto alloc = [&](size_t bytes) {
    void* p = ws + off;
    off = (off + bytes + 255) & ~(size_t)255;
    return p;
  };
  ushort*        xp_ws  = (ushort*)alloc(65536ull * 1024 * 2);
  uint32_t*      hs8u   = (uint32_t*)alloc(128ull * 512 * 64 * 4);
  ushort*        emb_bf = (ushort*)alloc(32000ull * 128 * 2);
  ushort*        W0p    = (ushort*)alloc(1024ull * 128 * 2);
  unsigned char* W1p8   = (unsigned char*)alloc(1024ull * 256);
  float*         b0p    = (float*)alloc(1024 * 4);
  float*         b1p    = (float*)alloc(1024 * 4);
  int*           idx_ws = (int*)alloc(65536 * 4);
  unsigned int*  done0  = (unsigned int*)alloc(128 * 4);

  prep_kernel<<<512, 256, 0, stream>>>(emb, x, Wih0, Wih1, bih0, bhh0, bih1, bhh1,
                                       emb_bf, idx_ws, W0p, W1p8, b0p, b1p, done0);
  gemm_xp<128, true><<<dim3(512, 8), 256, 0, stream>>>(emb_bf, idx_ws, W0p, b0p, xp_ws);
  mega_scan<<<256, 1024, 0, stream>>>(xp_ws, Whh0, Whh1, W1p8, b1p, hs8u, done0,
                                      fcw, fcb, (float*)d_out);
}